// Round 4
// baseline (4287.512 us; speedup 1.0000x reference)
//
#include <hip/hip_runtime.h>
#include <cstdint>
#include <cstddef>

#define NB 128
#define NC 16
#define NT 2048
#define NH 256
#define NG 1024
#define NO 10

typedef _Float16 f16;
typedef _Float16 h2 __attribute__((ext_vector_type(2)));
typedef _Float16 h4 __attribute__((ext_vector_type(4)));
typedef _Float16 h8 __attribute__((ext_vector_type(8)));

// h copies: stride 272 f16 = 544 B => copy-to-copy bank shift = 136 % 32 = 8
#define HSTRIDE 272

static __device__ __forceinline__ float fdot2(h2 a, h2 b, float c) {
#if __has_builtin(__builtin_amdgcn_fdot2)
  return __builtin_amdgcn_fdot2(a, b, c, false);
#else
  return c + (float)a[0] * (float)b[0] + (float)a[1] * (float)b[1];
#endif
}

// VALU lane swaps within a quad via DPP quad_perm (no DS-pipe traffic).
static __device__ __forceinline__ float qswap1(float v) {  // lanes ^1
  int r = __builtin_amdgcn_update_dpp(0, __builtin_bit_cast(int, v),
                                      0xB1, 0xF, 0xF, true);
  return __builtin_bit_cast(float, r);
}
static __device__ __forceinline__ float qswap2(float v) {  // lanes ^2
  int r = __builtin_amdgcn_update_dpp(0, __builtin_bit_cast(int, v),
                                      0x4E, 0xF, 0xF, true);
  return __builtin_bit_cast(float, r);
}

static __device__ __forceinline__ float sigm(float x) {
  return __builtin_amdgcn_rcpf(1.f + __expf(-x));
}
static __device__ __forceinline__ float tanh_(float x) {
  return 1.f - 2.f * __builtin_amdgcn_rcpf(1.f + __expf(2.f * x));
}

// Repack w_hh (1024x256 fp32, row-major) into k-chunk-major f16:
//   wp[((k>>3)*1024 + row)*8 + (k&7)] = (f16) w_hh[row*256 + k]
__global__ void prepack_whh(const float* __restrict__ whh, f16* __restrict__ wp) {
  int row = blockIdx.x;   // 0..1023
  int k   = threadIdx.x;  // 0..255
  float v = whh[row * NH + k];
  wp[((size_t)(k >> 3) * NG + (size_t)row) * 8 + (k & 7)] = (f16)v;
}

// One workgroup per batch, 1024 threads (16 waves -> 4 waves/SIMD).
// Thread t = 4*u + q owns hidden unit u and k-quarter q (k in [64q,64q+64)).
// i,f,g quarter-rows in VGPRs (96 h2 regs, inside the 128-reg budget so no
// AGPR round-trips); o quarter-rows stream from LDS thread-major
// (lane-contiguous b128 = conflict-free); h kept as 4 bank-offset copies
// (stride 272 f16) so quad reads/writes are bank-disjoint. Quad-reduce gate
// sums with a 2-stage DPP butterfly (bit-identical on all 4 lanes, so the
// redundant per-lane cell state cannot diverge).
__global__ __launch_bounds__(1024, 4)
void lstm_main(const float* __restrict__ x,
               const float* __restrict__ w_ih,
               const float* __restrict__ b_ih,
               const float* __restrict__ b_hh,
               const float* __restrict__ w_out,
               const float* __restrict__ b_out,
               const f16* __restrict__ wp,
               float* __restrict__ out) {
  const int t = threadIdx.x;   // 0..1023
  const int u = t >> 2;        // hidden unit 0..255
  const int q = t & 3;         // k-quarter
  const int b = blockIdx.x;

  __shared__ __align__(16) f16 olds[8][1024][8];     // 128 KB, [kchunk][thread][8]
  __shared__ __align__(16) f16 hq[2][4][HSTRIDE];    // 4.25 KB, 4 bank-offset copies
  __shared__ __align__(16) f16 xs[64][NC];           // 2 KB
  __shared__ float hT[NH];
  __shared__ float lg[NO];

  // ---------------- one-time loads ----------------
  h2 wi_[32], wf_[32], wg_[32];  // i,f,g quarter-rows (32 packed pairs each)
  h2 wih[4][2];                  // w_ih quarter-rows (4 ch = 2 pairs) x 4 gates
  const h8* wp8 = (const h8*)wp;
#pragma unroll
  for (int c = 0; c < 8; ++c) {
    int gc = 8 * q + c;  // global k-chunk
    h8 vi = wp8[(size_t)gc * NG + u];
    h8 vf = wp8[(size_t)gc * NG + 256 + u];
    h8 vg = wp8[(size_t)gc * NG + 512 + u];
    h8 vo = wp8[(size_t)gc * NG + 768 + u];
#pragma unroll
    for (int uu = 0; uu < 4; ++uu) {
      h2 ti = {vi[2 * uu], vi[2 * uu + 1]}; wi_[4 * c + uu] = ti;
      h2 tf = {vf[2 * uu], vf[2 * uu + 1]}; wf_[4 * c + uu] = tf;
      h2 tg = {vg[2 * uu], vg[2 * uu + 1]}; wg_[4 * c + uu] = tg;
    }
    *(h8*)&olds[c][t][0] = vo;  // read back only by this thread
  }
#pragma unroll
  for (int g4 = 0; g4 < 4; ++g4) {
    int row = u + 256 * g4;
#pragma unroll
    for (int uu = 0; uu < 2; ++uu) {
      h2 t2 = {(f16)w_ih[row * NC + 4 * q + 2 * uu],
               (f16)w_ih[row * NC + 4 * q + 2 * uu + 1]};
      wih[g4][uu] = t2;
    }
  }
  // biases only in quarter 0 (added exactly once per gate sum)
  float bi_ = q ? 0.f : b_ih[u] + b_hh[u];
  float bf_ = q ? 0.f : b_ih[256 + u] + b_hh[256 + u];
  float bg_ = q ? 0.f : b_ih[512 + u] + b_hh[512 + u];
  float bo_ = q ? 0.f : b_ih[768 + u] + b_hh[768 + u];

  // zero h copies, stage x chunk 0 (one element per thread)
  for (int e = t; e < 2 * 4 * HSTRIDE; e += 1024) ((f16*)hq)[e] = (f16)0.f;
  {
    int cc = t >> 6, tt = t & 63;
    xs[tt][cc] = (f16)x[(size_t)(b * NC + cc) * NT + tt];
  }
  __syncthreads();

  // ---------------- recurrence ----------------
  float c_ = 0.f, h_last = 0.f;
  const h8* obase = (const h8*)&olds[0][t][0];           // chunk stride = 1024 h8
  // read base inside copy q: element offset 64*q (this thread's k-range)
  const f16* hrd[2] = {&hq[0][q][64 * q], &hq[1][q][64 * q]};
  f16* hwr[2] = {&hq[0][q][u], &hq[1][q][u]};

#pragma unroll 1
  for (int s = 0; s < NT; ++s) {
    const int p = s & 1;
    // anti-LICM: opaque zero so the (constant) o-weight LDS reads can't be
    // hoisted out of the loop into registers.
    int zero = 0;
    asm volatile("" : "+s"(zero));
    const h8* ob = obase + zero;
    const h8* hsrc = (const h8*)hrd[p];

    float ai = bi_, af = bf_, ag = bg_, ao = bo_;

    // x projection: this quarter's 4 channels = 2 f16 pairs
    {
      h4 xv = *(const h4*)&xs[s & 63][4 * q];
      h2 xp0 = {xv[0], xv[1]};
      h2 xp1 = {xv[2], xv[3]};
      ai = fdot2(xp0, wih[0][0], ai); ai = fdot2(xp1, wih[0][1], ai);
      af = fdot2(xp0, wih[1][0], af); af = fdot2(xp1, wih[1][1], af);
      ag = fdot2(xp0, wih[2][0], ag); ag = fdot2(xp1, wih[2][1], ag);
      ao = fdot2(xp0, wih[3][0], ao); ao = fdot2(xp1, wih[3][1], ao);
    }

    // recurrent dots over this thread's 64-wide k-quarter
#pragma unroll
    for (int c = 0; c < 8; ++c) {
      h8 hv = hsrc[c];                  // 4 bank-disjoint broadcast addrs/wave
      h8 ov = ob[(size_t)c * 1024];     // lane-contiguous: conflict-free
#pragma unroll
      for (int uu = 0; uu < 4; ++uu) {
        h2 hp = {hv[2 * uu], hv[2 * uu + 1]};
        h2 op = {ov[2 * uu], ov[2 * uu + 1]};
        ai = fdot2(hp, wi_[4 * c + uu], ai);
        af = fdot2(hp, wf_[4 * c + uu], af);
        ag = fdot2(hp, wg_[4 * c + uu], ag);
        ao = fdot2(hp, op, ao);
      }
    }

    // quad reduction (lanes 4u..4u+3) via DPP butterfly; result identical
    // bit-for-bit on all 4 lanes.
    ai += qswap1(ai); af += qswap1(af); ag += qswap1(ag); ao += qswap1(ao);
    ai += qswap2(ai); af += qswap2(af); ag += qswap2(ag); ao += qswap2(ao);

    float ig = sigm(ai);
    float fg = sigm(af);
    float gv = tanh_(ag);
    float og = sigm(ao);
    c_ = fg * c_ + ig * gv;
    float hh = og * tanh_(c_);
    hwr[1 - p][0] = (f16)hh;  // each lane updates its own copy q
    h_last = hh;

    // restage x every 64 steps (extra barrier protects WAR on xs)
    if ((s & 63) == 63 && s != NT - 1) {
      __syncthreads();
      int cc = t >> 6, tt = t & 63;
      xs[tt][cc] = (f16)x[(size_t)(b * NC + cc) * NT + (s + 1) + tt];
    }
    __syncthreads();
  }

  // ---------------- head: logits + log_softmax ----------------
  if (q == 0) hT[u] = h_last;
  __syncthreads();
  if (t < NO) {
    float acc = b_out[t];
    for (int k = 0; k < NH; ++k) acc += hT[k] * w_out[t * NH + k];
    lg[t] = acc;
  }
  __syncthreads();
  if (t == 0) {
    float m = lg[0];
    for (int o = 1; o < NO; ++o) m = fmaxf(m, lg[o]);
    float ssum = 0.f;
    for (int o = 0; o < NO; ++o) ssum += __expf(lg[o] - m);
    float lse = m + __logf(ssum);
    for (int o = 0; o < NO; ++o) out[b * NO + o] = lg[o] - lse;
  }
}

extern "C" void kernel_launch(void* const* d_in, const int* in_sizes, int n_in,
                              void* d_out, int out_size, void* d_ws, size_t ws_size,
                              hipStream_t stream) {
  const float* x    = (const float*)d_in[0];
  const float* wih  = (const float*)d_in[1];
  const float* whh  = (const float*)d_in[2];
  const float* bih  = (const float*)d_in[3];
  const float* bhh  = (const float*)d_in[4];
  const float* wout = (const float*)d_in[5];
  const float* bout = (const float*)d_in[6];
  float* out = (float*)d_out;
  f16* wp = (f16*)d_ws;  // 512 KB f16 repack of w_hh

  hipLaunchKernelGGL(prepack_whh, dim3(NG), dim3(NH), 0, stream, whh, wp);
  hipLaunchKernelGGL(lstm_main, dim3(NB), dim3(1024), 0, stream,
                     x, wih, bih, bhh, wout, bout, wp, out);
}

// Round 5
// 2310.774 us; speedup vs baseline: 1.8554x; 1.8554x over previous
//
#include <hip/hip_runtime.h>
#include <cstdint>
#include <cstddef>

#define NB 128
#define NC 16
#define NT 2048
#define NH 256
#define NG 1024
#define NO 10

typedef _Float16 f16;
typedef _Float16 h2 __attribute__((ext_vector_type(2)));
typedef _Float16 f16x4 __attribute__((ext_vector_type(4)));

// h i8 copies: stride 272 B; quad q reads at byte 336q -> dword 84q -> banks
// {0,20,8,28}+[0..3] disjoint; writes at dword 68q -> 4-bank groups disjoint.
#define HCOPY 272
#define HBUF 1088  // 4 copies

static __device__ __forceinline__ float fdot2(h2 a, h2 b, float c) {
#if __has_builtin(__builtin_amdgcn_fdot2)
  return __builtin_amdgcn_fdot2(a, b, c, false);
#else
  return c + (float)a[0] * (float)b[0] + (float)a[1] * (float)b[1];
#endif
}

static __device__ __forceinline__ int sdot4(int a, int b, int c) {
#if __has_builtin(__builtin_amdgcn_sdot4)
  return __builtin_amdgcn_sdot4(a, b, c, false);
#else
  int r = c;
#pragma unroll
  for (int i = 0; i < 4; ++i)
    r += (int)(int8_t)(a >> (8 * i)) * (int)(int8_t)(b >> (8 * i));
  return r;
#endif
}

// VALU lane swaps within a quad via DPP quad_perm (no DS-pipe traffic).
static __device__ __forceinline__ float qswap1(float v) {  // lanes ^1
  int r = __builtin_amdgcn_update_dpp(0, __builtin_bit_cast(int, v),
                                      0xB1, 0xF, 0xF, true);
  return __builtin_bit_cast(float, r);
}
static __device__ __forceinline__ float qswap2(float v) {  // lanes ^2
  int r = __builtin_amdgcn_update_dpp(0, __builtin_bit_cast(int, v),
                                      0x4E, 0xF, 0xF, true);
  return __builtin_bit_cast(float, r);
}

static __device__ __forceinline__ float sigm(float x) {
  return __builtin_amdgcn_rcpf(1.f + __expf(-x));
}
static __device__ __forceinline__ float tanh_(float x) {
  return 1.f - 2.f * __builtin_amdgcn_rcpf(1.f + __expf(2.f * x));
}

// Quantize w_hh (1024x256 f32 row-major) to i8 with per-row scale.
// wq[row][k] = round(w / s_row), scale[row] = s_row = max|row| / 127.
__global__ void prepack_whh_i8(const float* __restrict__ whh,
                               int8_t* __restrict__ wq,
                               float* __restrict__ scale) {
  int row = blockIdx.x;   // 0..1023
  int k   = threadIdx.x;  // 0..255
  float v = whh[row * NH + k];
  float m = fabsf(v);
  for (int off = 32; off; off >>= 1) m = fmaxf(m, __shfl_xor(m, off, 64));
  __shared__ float smax[4];
  if ((k & 63) == 0) smax[k >> 6] = m;
  __syncthreads();
  float mm = fmaxf(fmaxf(smax[0], smax[1]), fmaxf(smax[2], smax[3]));
  float s = fmaxf(mm, 1e-20f) / 127.f;
  int qv = (int)rintf(v / s);
  qv = min(127, max(-127, qv));
  wq[row * NH + k] = (int8_t)qv;
  if (k == 0) scale[row] = s;
}

// One workgroup per batch, 1024 threads (16 waves, 4 waves/SIMD; VGPR budget
// 128). Thread t = 4u+q owns hidden unit u and k-quarter q (64 wide).
// i,f,g quarter-rows in VGPRs as packed i8 (16 ints each = 48 regs);
// o quarter-rows stream from LDS thread-major (lane-contiguous b128);
// h kept as i8 in 4 bank-offset copies (bank-disjoint quad reads/writes).
// Recurrent dots: v_dot4_i32_i8 into i32; dequant per lane with
// scale[row]/127, add f16-dot2 x-projection + bias, DPP quad-reduce (f32,
// bit-identical on all 4 lanes -> redundant cell state cannot diverge).
__global__ __launch_bounds__(1024, 4)
void lstm_main(const float* __restrict__ x,
               const float* __restrict__ w_ih,
               const float* __restrict__ b_ih,
               const float* __restrict__ b_hh,
               const float* __restrict__ w_out,
               const float* __restrict__ b_out,
               const int8_t* __restrict__ wq,
               const float* __restrict__ scales,
               float* __restrict__ out) {
  const int t = threadIdx.x;   // 0..1023
  const int u = t >> 2;        // hidden unit 0..255
  const int q = t & 3;         // k-quarter
  const int b = blockIdx.x;

  __shared__ __align__(16) int8_t olds[4][1024][16];  // 64 KB o rows
  __shared__ __align__(16) int8_t hq8[2 * HBUF];      // 2.2 KB h copies
  __shared__ __align__(16) f16 xs[64][NC];            // 2 KB
  __shared__ float hT[NH];
  __shared__ float lg[NO];

  // ---------------- one-time loads ----------------
  int wi_[16], wf_[16], wg_[16];  // i,f,g quarter-rows, packed 4xi8 per int
  h2 wih[4][2];                   // w_ih quarter-rows (4 ch = 2 pairs) x 4
  {
    const int4* pi = (const int4*)(wq + (size_t)u * NH + 64 * q);
    const int4* pf = (const int4*)(wq + (size_t)(256 + u) * NH + 64 * q);
    const int4* pg = (const int4*)(wq + (size_t)(512 + u) * NH + 64 * q);
    const int4* po = (const int4*)(wq + (size_t)(768 + u) * NH + 64 * q);
#pragma unroll
    for (int c = 0; c < 4; ++c) {
      int4 vi = pi[c], vf = pf[c], vg = pg[c], vo = po[c];
      wi_[4 * c + 0] = vi.x; wi_[4 * c + 1] = vi.y; wi_[4 * c + 2] = vi.z; wi_[4 * c + 3] = vi.w;
      wf_[4 * c + 0] = vf.x; wf_[4 * c + 1] = vf.y; wf_[4 * c + 2] = vf.z; wf_[4 * c + 3] = vf.w;
      wg_[4 * c + 0] = vg.x; wg_[4 * c + 1] = vg.y; wg_[4 * c + 2] = vg.z; wg_[4 * c + 3] = vg.w;
      *(int4*)&olds[c][t][0] = vo;  // read back only by this thread
    }
  }
#pragma unroll
  for (int g4 = 0; g4 < 4; ++g4) {
    int row = u + 256 * g4;
#pragma unroll
    for (int uu = 0; uu < 2; ++uu) {
      h2 t2 = {(f16)w_ih[row * NC + 4 * q + 2 * uu],
               (f16)w_ih[row * NC + 4 * q + 2 * uu + 1]};
      wih[g4][uu] = t2;
    }
  }
  const float K = 1.f / 127.f;
  float sci = scales[u] * K;
  float scf = scales[256 + u] * K;
  float scg = scales[512 + u] * K;
  float sco = scales[768 + u] * K;
  // biases only in quarter 0 (added exactly once per gate sum)
  float bi_ = q ? 0.f : b_ih[u] + b_hh[u];
  float bf_ = q ? 0.f : b_ih[256 + u] + b_hh[256 + u];
  float bg_ = q ? 0.f : b_ih[512 + u] + b_hh[512 + u];
  float bo_ = q ? 0.f : b_ih[768 + u] + b_hh[768 + u];

  // zero h copies (both phases), stage x chunk 0
  for (int e = t; e < 2 * HBUF; e += 1024) hq8[e] = 0;
  {
    int cc = t >> 6, tt = t & 63;
    xs[tt][cc] = (f16)x[(size_t)(b * NC + cc) * NT + tt];
  }
  __syncthreads();

  // ---------------- recurrence ----------------
  float c_ = 0.f, h_last = 0.f;
  const int rdoff = 336 * q;        // copy q + this quarter's k-start
  const int wroff = HCOPY * q + u;  // byte slot in copy q

#pragma unroll 1
  for (int s = 0; s < NT; ++s) {
    const int p = s & 1;
    // anti-LICM: opaque zero so the (constant) o-weight LDS reads can't be
    // hoisted out of the loop into registers (VGPR budget is tight).
    int zero = 0;
    asm volatile("" : "+s"(zero));
    const int4* ob = (const int4*)&olds[0][0][0] + zero + t;
    const int4* hrd = (const int4*)(hq8 + p * HBUF + rdoff);

    float fi = bi_, ff = bf_, fg_ = bg_, fo = bo_;
    // x projection: this quarter's 4 channels = 2 f16 pairs (f32 acc)
    {
      f16x4 xv = *(const f16x4*)&xs[s & 63][4 * q];
      h2 xp0 = {xv[0], xv[1]};
      h2 xp1 = {xv[2], xv[3]};
      fi = fdot2(xp0, wih[0][0], fi); fi = fdot2(xp1, wih[0][1], fi);
      ff = fdot2(xp0, wih[1][0], ff); ff = fdot2(xp1, wih[1][1], ff);
      fg_ = fdot2(xp0, wih[2][0], fg_); fg_ = fdot2(xp1, wih[2][1], fg_);
      fo = fdot2(xp0, wih[3][0], fo); fo = fdot2(xp1, wih[3][1], fo);
    }

    // recurrent dots over this thread's 64-wide k-quarter (i8 x i8 -> i32)
    int ai = 0, af = 0, ag = 0, ao = 0;
#pragma unroll
    for (int c = 0; c < 4; ++c) {
      int4 hv = hrd[c];             // 4 bank-disjoint broadcast addrs/wave
      int4 ov = ob[c * 1024];       // lane-contiguous: conflict-free
      ai = sdot4(hv.x, wi_[4 * c + 0], ai); ai = sdot4(hv.y, wi_[4 * c + 1], ai);
      ai = sdot4(hv.z, wi_[4 * c + 2], ai); ai = sdot4(hv.w, wi_[4 * c + 3], ai);
      af = sdot4(hv.x, wf_[4 * c + 0], af); af = sdot4(hv.y, wf_[4 * c + 1], af);
      af = sdot4(hv.z, wf_[4 * c + 2], af); af = sdot4(hv.w, wf_[4 * c + 3], af);
      ag = sdot4(hv.x, wg_[4 * c + 0], ag); ag = sdot4(hv.y, wg_[4 * c + 1], ag);
      ag = sdot4(hv.z, wg_[4 * c + 2], ag); ag = sdot4(hv.w, wg_[4 * c + 3], ag);
      ao = sdot4(hv.x, ov.x, ao); ao = sdot4(hv.y, ov.y, ao);
      ao = sdot4(hv.z, ov.z, ao); ao = sdot4(hv.w, ov.w, ao);
    }

    // dequantize per lane, then quad-reduce (lanes 4u..4u+3) via DPP;
    // result bit-identical on all 4 lanes.
    float vi = fi + (float)ai * sci;
    float vf = ff + (float)af * scf;
    float vg = fg_ + (float)ag * scg;
    float vo = fo + (float)ao * sco;
    vi += qswap1(vi); vf += qswap1(vf); vg += qswap1(vg); vo += qswap1(vo);
    vi += qswap2(vi); vf += qswap2(vf); vg += qswap2(vg); vo += qswap2(vo);

    float ig = sigm(vi);
    float fgate = sigm(vf);
    float gv = tanh_(vg);
    float og = sigm(vo);
    c_ = fgate * c_ + ig * gv;
    float hh = og * tanh_(c_);
    h_last = hh;
    // quantize h (|hh| < 1 so no clamp needed); each lane updates its copy q
    hq8[(1 - p) * HBUF + wroff] = (int8_t)(int)rintf(hh * 127.f);

    // restage x every 64 steps (extra barrier protects WAR on xs)
    if ((s & 63) == 63 && s != NT - 1) {
      __syncthreads();
      int cc = t >> 6, tt = t & 63;
      xs[tt][cc] = (f16)x[(size_t)(b * NC + cc) * NT + (s + 1) + tt];
    }
    __syncthreads();
  }

  // ---------------- head: logits + log_softmax ----------------
  if (q == 0) hT[u] = h_last;
  __syncthreads();
  if (t < NO) {
    float acc = b_out[t];
    for (int k = 0; k < NH; ++k) acc += hT[k] * w_out[t * NH + k];
    lg[t] = acc;
  }
  __syncthreads();
  if (t == 0) {
    float m = lg[0];
    for (int o = 1; o < NO; ++o) m = fmaxf(m, lg[o]);
    float ssum = 0.f;
    for (int o = 0; o < NO; ++o) ssum += __expf(lg[o] - m);
    float lse = m + __logf(ssum);
    for (int o = 0; o < NO; ++o) out[b * NO + o] = lg[o] - lse;
  }
}

extern "C" void kernel_launch(void* const* d_in, const int* in_sizes, int n_in,
                              void* d_out, int out_size, void* d_ws, size_t ws_size,
                              hipStream_t stream) {
  const float* x    = (const float*)d_in[0];
  const float* wih  = (const float*)d_in[1];
  const float* whh  = (const float*)d_in[2];
  const float* bih  = (const float*)d_in[3];
  const float* bhh  = (const float*)d_in[4];
  const float* wout = (const float*)d_in[5];
  const float* bout = (const float*)d_in[6];
  float* out = (float*)d_out;
  int8_t* wq = (int8_t*)d_ws;                    // 256 KB i8 w_hh
  float* scales = (float*)((char*)d_ws + NG * NH);  // 4 KB row scales

  hipLaunchKernelGGL(prepack_whh_i8, dim3(NG), dim3(NH), 0, stream, whh, wq, scales);
  hipLaunchKernelGGL(lstm_main, dim3(NB), dim3(1024), 0, stream,
                     x, wih, bih, bhh, wout, bout, wq, scales, out);
}

// Round 7
// 1809.722 us; speedup vs baseline: 2.3692x; 1.2769x over previous
//
#include <hip/hip_runtime.h>
#include <cstdint>
#include <cstddef>

#define NB 128
#define NC 16
#define NT 2048
#define NH 256
#define NG 1024
#define NO 10

typedef _Float16 f16;
typedef _Float16 h2 __attribute__((ext_vector_type(2)));
typedef _Float16 h8 __attribute__((ext_vector_type(8)));

// h state: i8[256] per phase, TWO bank-offset copies per phase.
//   phase stride 544 B, copy offsets {0, 272}.
// Reads (int4, 16B-aligned): half0 at 544p + 16c  -> banks {4c..4c+3} (+8p)
//                            half1 at 544p + 400 + 16c -> banks {4c+4..4c+7} (+8p)
//   -> bank-disjoint per instruction, broadcast within each half.
#define HPHASE 544

static __device__ __forceinline__ float fdot2(h2 a, h2 b, float c) {
#if __has_builtin(__builtin_amdgcn_fdot2)
  return __builtin_amdgcn_fdot2(a, b, c, false);
#else
  return c + (float)a[0] * (float)b[0] + (float)a[1] * (float)b[1];
#endif
}

static __device__ __forceinline__ int sdot4(int a, int b, int c) {
#if __has_builtin(__builtin_amdgcn_sdot4)
  return __builtin_amdgcn_sdot4(a, b, c, false);
#else
  int r = c;
#pragma unroll
  for (int i = 0; i < 4; ++i)
    r += (int)(int8_t)(a >> (8 * i)) * (int)(int8_t)(b >> (8 * i));
  return r;
#endif
}

// VALU lane swap 2k<->2k+1 via DPP quad_perm [1,0,3,2] (no DS traffic).
static __device__ __forceinline__ float pairswap(float v) {
  int r = __builtin_amdgcn_update_dpp(0, __builtin_bit_cast(int, v),
                                      0xB1, 0xF, 0xF, true);
  return __builtin_bit_cast(float, r);
}

static __device__ __forceinline__ float sigm(float x) {
  return __builtin_amdgcn_rcpf(1.f + __expf(-x));
}
static __device__ __forceinline__ float tanh_(float x) {
  return 1.f - 2.f * __builtin_amdgcn_rcpf(1.f + __expf(2.f * x));
}

// Quantize w_hh (1024x256 f32 row-major) to i8 with per-row scale.
__global__ void prepack_whh_i8(const float* __restrict__ whh,
                               int8_t* __restrict__ wq,
                               float* __restrict__ scale) {
  int row = blockIdx.x;   // 0..1023
  int k   = threadIdx.x;  // 0..255
  float v = whh[row * NH + k];
  float m = fabsf(v);
  for (int off = 32; off; off >>= 1) m = fmaxf(m, __shfl_xor(m, off, 64));
  __shared__ float smax[4];
  if ((k & 63) == 0) smax[k >> 6] = m;
  __syncthreads();
  float mm = fmaxf(fmaxf(smax[0], smax[1]), fmaxf(smax[2], smax[3]));
  float s = fmaxf(mm, 1e-20f) / 127.f;
  int qv = (int)rintf(v / s);
  qv = min(127, max(-127, qv));
  wq[row * NH + k] = (int8_t)qv;
  if (k == 0) scale[row] = s;
}

// One workgroup per batch, 512 threads (8 waves -> 2 waves/SIMD).
// launch_bounds(512,1): allocator budget 512 regs so ALL FOUR i8 gate
// half-rows (128 ints) stay in ARCH VGPRs — no AGPR round-trips (R5's
// +64 v_accvgpr_read/step) and no spill. Thread t = 2u+half owns hidden
// unit u, k-half `half` (128 wide). h is i8 in 2 bank-offset LDS copies;
// v_dot4_i32_i8 -> i32, dequant by scale[row]/127, DPP pair-reduce (f32,
// bit-identical on both lanes so the redundant cell state can't diverge).
__global__ __launch_bounds__(512, 1)
void lstm_main(const float* __restrict__ x,
               const float* __restrict__ w_ih,
               const float* __restrict__ b_ih,
               const float* __restrict__ b_hh,
               const float* __restrict__ w_out,
               const float* __restrict__ b_out,
               const int8_t* __restrict__ wq,
               const float* __restrict__ scales,
               float* __restrict__ out) {
  const int t = threadIdx.x;   // 0..511
  const int u = t >> 1;        // hidden unit 0..255
  const int half = t & 1;      // k-half
  const int b = blockIdx.x;

  __shared__ __align__(16) int8_t hq8[2 * HPHASE];  // 1.1 KB h copies
  __shared__ __align__(16) f16 xs[64][NC];          // 2 KB staged x
  __shared__ float hT[NH];
  __shared__ float lg[NO];

  // ---------------- one-time loads ----------------
  int wi_[32], wf_[32], wg_[32], wo_[32];  // 4 gate half-rows, packed i8x4
  h2 wih[4][4];                            // w_ih half-rows (8 ch) x 4 gates
  {
    const int4* pi = (const int4*)(wq + (size_t)u * NH + 128 * half);
    const int4* pf = (const int4*)(wq + (size_t)(256 + u) * NH + 128 * half);
    const int4* pg = (const int4*)(wq + (size_t)(512 + u) * NH + 128 * half);
    const int4* po = (const int4*)(wq + (size_t)(768 + u) * NH + 128 * half);
#pragma unroll
    for (int c = 0; c < 8; ++c) {
      int4 vi = pi[c], vf = pf[c], vg = pg[c], vo = po[c];
      wi_[4 * c + 0] = vi.x; wi_[4 * c + 1] = vi.y; wi_[4 * c + 2] = vi.z; wi_[4 * c + 3] = vi.w;
      wf_[4 * c + 0] = vf.x; wf_[4 * c + 1] = vf.y; wf_[4 * c + 2] = vf.z; wf_[4 * c + 3] = vf.w;
      wg_[4 * c + 0] = vg.x; wg_[4 * c + 1] = vg.y; wg_[4 * c + 2] = vg.z; wg_[4 * c + 3] = vg.w;
      wo_[4 * c + 0] = vo.x; wo_[4 * c + 1] = vo.y; wo_[4 * c + 2] = vo.z; wo_[4 * c + 3] = vo.w;
    }
  }
#pragma unroll
  for (int g4 = 0; g4 < 4; ++g4) {
    int row = u + 256 * g4;
#pragma unroll
    for (int uu = 0; uu < 4; ++uu) {
      h2 t2 = {(f16)w_ih[row * NC + 8 * half + 2 * uu],
               (f16)w_ih[row * NC + 8 * half + 2 * uu + 1]};
      wih[g4][uu] = t2;
    }
  }
  const float K = 1.f / 127.f;
  float sci = scales[u] * K;
  float scf = scales[256 + u] * K;
  float scg = scales[512 + u] * K;
  float sco = scales[768 + u] * K;
  // biases only in half 0 (added exactly once per gate sum)
  float bi_ = half ? 0.f : b_ih[u] + b_hh[u];
  float bf_ = half ? 0.f : b_ih[256 + u] + b_hh[256 + u];
  float bg_ = half ? 0.f : b_ih[512 + u] + b_hh[512 + u];
  float bo_ = half ? 0.f : b_ih[768 + u] + b_hh[768 + u];

  // zero h copies (both phases), stage x chunk 0
  for (int e = t; e < 2 * HPHASE; e += 512) hq8[e] = 0;
#pragma unroll
  for (int r = 0; r < 2; ++r) {
    int e = t + 512 * r;  // 0..1023 over (c, tt)
    int cc = e >> 6, tt = e & 63;
    xs[tt][cc] = (f16)x[(size_t)(b * NC + cc) * NT + tt];
  }
  __syncthreads();

  // ---------------- recurrence ----------------
  float c_ = 0.f, h_last = 0.f;
  const int rdoff = 400 * half;        // copy(half) + k-range offset, 16B-aligned
  const int wroff = 272 * half + u;    // byte slot in copy(half)

#pragma unroll 1
  for (int s = 0; s < NT; ++s) {
    const int p = s & 1;
    const int4* hrd = (const int4*)(hq8 + p * HPHASE + rdoff);

    float fi = bi_, ff = bf_, fg_ = bg_, fo = bo_;
    // x projection: this half's 8 channels = 4 f16 pairs (f32 acc)
    {
      h8 xv = *(const h8*)&xs[s & 63][8 * half];
#pragma unroll
      for (int uu = 0; uu < 4; ++uu) {
        h2 xp = {xv[2 * uu], xv[2 * uu + 1]};
        fi = fdot2(xp, wih[0][uu], fi);
        ff = fdot2(xp, wih[1][uu], ff);
        fg_ = fdot2(xp, wih[2][uu], fg_);
        fo = fdot2(xp, wih[3][uu], fo);
      }
    }

    // recurrent dots over this thread's 128-wide k-half (i8 x i8 -> i32)
    int ai = 0, af = 0, ag = 0, ao = 0;
#pragma unroll
    for (int c = 0; c < 8; ++c) {
      int4 hv = hrd[c];  // 2 bank-disjoint broadcast addrs/wave
      ai = sdot4(hv.x, wi_[4 * c + 0], ai); ai = sdot4(hv.y, wi_[4 * c + 1], ai);
      ai = sdot4(hv.z, wi_[4 * c + 2], ai); ai = sdot4(hv.w, wi_[4 * c + 3], ai);
      af = sdot4(hv.x, wf_[4 * c + 0], af); af = sdot4(hv.y, wf_[4 * c + 1], af);
      af = sdot4(hv.z, wf_[4 * c + 2], af); af = sdot4(hv.w, wf_[4 * c + 3], af);
      ag = sdot4(hv.x, wg_[4 * c + 0], ag); ag = sdot4(hv.y, wg_[4 * c + 1], ag);
      ag = sdot4(hv.z, wg_[4 * c + 2], ag); ag = sdot4(hv.w, wg_[4 * c + 3], ag);
      ao = sdot4(hv.x, wo_[4 * c + 0], ao); ao = sdot4(hv.y, wo_[4 * c + 1], ao);
      ao = sdot4(hv.z, wo_[4 * c + 2], ao); ao = sdot4(hv.w, wo_[4 * c + 3], ao);
    }

    // dequantize per lane, then pair-reduce (lanes 2u,2u+1) via DPP;
    // result bit-identical on both lanes.
    float vi = fi + (float)ai * sci;
    float vf = ff + (float)af * scf;
    float vg = fg_ + (float)ag * scg;
    float vo = fo + (float)ao * sco;
    vi += pairswap(vi); vf += pairswap(vf); vg += pairswap(vg); vo += pairswap(vo);

    float ig = sigm(vi);
    float fgate = sigm(vf);
    float gv = tanh_(vg);
    float og = sigm(vo);
    c_ = fgate * c_ + ig * gv;
    float hh = og * tanh_(c_);
    h_last = hh;
    // quantize h (|hh| < 1); each lane updates its own copy(half)
    hq8[(1 - p) * HPHASE + wroff] = (int8_t)(int)rintf(hh * 127.f);

    // restage x every 64 steps (extra barrier protects WAR on xs)
    if ((s & 63) == 63 && s != NT - 1) {
      __syncthreads();
#pragma unroll
      for (int r = 0; r < 2; ++r) {
        int e = t + 512 * r;
        int cc = e >> 6, tt = e & 63;
        xs[tt][cc] = (f16)x[(size_t)(b * NC + cc) * NT + (s + 1) + tt];
      }
    }
    __syncthreads();
  }

  // ---------------- head: logits + log_softmax ----------------
  if (!half) hT[u] = h_last;
  __syncthreads();
  if (t < NO) {
    float acc = b_out[t];
    for (int k = 0; k < NH; ++k) acc += hT[k] * w_out[t * NH + k];
    lg[t] = acc;
  }
  __syncthreads();
  if (t == 0) {
    float m = lg[0];
    for (int o = 1; o < NO; ++o) m = fmaxf(m, lg[o]);
    float ssum = 0.f;
    for (int o = 0; o < NO; ++o) ssum += __expf(lg[o] - m);
    float lse = m + __logf(ssum);
    for (int o = 0; o < NO; ++o) out[b * NO + o] = lg[o] - lse;
  }
}

extern "C" void kernel_launch(void* const* d_in, const int* in_sizes, int n_in,
                              void* d_out, int out_size, void* d_ws, size_t ws_size,
                              hipStream_t stream) {
  const float* x    = (const float*)d_in[0];
  const float* wih  = (const float*)d_in[1];
  const float* whh  = (const float*)d_in[2];
  const float* bih  = (const float*)d_in[3];
  const float* bhh  = (const float*)d_in[4];
  const float* wout = (const float*)d_in[5];
  const float* bout = (const float*)d_in[6];
  float* out = (float*)d_out;
  int8_t* wq = (int8_t*)d_ws;                       // 256 KB i8 w_hh
  float* scales = (float*)((char*)d_ws + NG * NH);  // 4 KB row scales

  hipLaunchKernelGGL(prepack_whh_i8, dim3(NG), dim3(NH), 0, stream, whh, wq, scales);
  hipLaunchKernelGGL(lstm_main, dim3(NB), dim3(512), 0, stream,
                     x, wih, bih, bhh, wout, bout, wq, scales, out);
}